// Round 1
// baseline (172.614 us; speedup 1.0000x reference)
//
#include <hip/hip_runtime.h>
#include <cmath>

#define BN 4096      // B*N
#define NN 64
#define GAUSS 25
#define FD 128

__device__ __forceinline__ float softplus_f(float x) {
    // jax.nn.softplus = logaddexp(x, 0) = max(x,0) + log1p(exp(-|x|))
    return fmaxf(x, 0.f) + log1pf(expf(-fabsf(x)));
}

// K1: x = emb[z]; write x to out[:, :128]; y = x @ w_in2f
__global__ __launch_bounds__(128) void k1_embed_y(
    const float* __restrict__ emb, const int* __restrict__ zn,
    const float* __restrict__ w_in2f, float* __restrict__ y,
    float* __restrict__ out)
{
    const int atom = blockIdx.x;
    const int f = threadIdx.x;
    __shared__ float s_x[FD];
    const int z = zn[atom];
    const float xv = emb[z * FD + f];
    s_x[f] = xv;
    out[(size_t)atom * 256 + f] = xv;
    __syncthreads();
    float acc = 0.f;
#pragma unroll 8
    for (int d = 0; d < FD; ++d)
        acc += s_x[d] * w_in2f[d * FD + f];
    y[atom * FD + f] = acc;
}

// K2: per-atom continuous-filter convolution with active-edge compaction
__global__ __launch_bounds__(256) void k2_conv(
    const float* __restrict__ pos, const float* __restrict__ cell,
    const float* __restrict__ coff, const float* __restrict__ nmask,
    const float* __restrict__ wf1, const float* __restrict__ bf1,
    const float* __restrict__ wf2, const float* __restrict__ bf2,
    const int* __restrict__ nbr, const float* __restrict__ y,
    float* __restrict__ agg)
{
    const int atom = blockIdx.x;
    const int b = atom >> 9;
    const int t = threadIdx.x;

    __shared__ float s_fij[NN][GAUSS];   // 6.4 KB
    __shared__ float s_h1[NN][FD];       // 32 KB
    __shared__ float s_red[16][FD];      // 8 KB
    __shared__ float s_r[NN];
    __shared__ float s_C[NN];
    __shared__ int   s_nb[NN];
    __shared__ int   s_cnt;

    // ---- phase 1: distances, cutoff mask, wave-0 ballot compaction ----
    if (t < NN) {
        const int k = t;
        const int nb = nbr[atom * NN + k];
        const float m = nmask[atom * NN + k];
        const float* cb = cell + b * 9;
        const float* co = coff + (size_t)(atom * NN + k) * 3;
        // off[x] = sum_a co[a] * cell[a][x]
        const float ox = co[0]*cb[0] + co[1]*cb[3] + co[2]*cb[6];
        const float oy = co[0]*cb[1] + co[1]*cb[4] + co[2]*cb[7];
        const float oz = co[0]*cb[2] + co[1]*cb[5] + co[2]*cb[8];
        const float* pj = pos + (size_t)((b << 9) + nb) * 3;
        const float* pi = pos + (size_t)atom * 3;
        const float dx = pj[0] + ox - pi[0];
        const float dy = pj[1] + oy - pi[1];
        const float dz = pj[2] + oz - pi[2];
        const float d2 = dx*dx + dy*dy + dz*dz;
        const float r = sqrtf(m > 0.f ? d2 : 1.0f) * m;
        const float C = (r < 5.0f) ? m : 0.f;
        const bool active = (C != 0.f);
        const unsigned long long bal = __ballot(active);
        const int pre = __popcll(bal & ((1ull << k) - 1ull));
        if (active) {
            s_r[pre]  = r;
            s_C[pre]  = C;
            s_nb[pre] = nb;
        }
        if (k == 0) s_cnt = __popcll(bal);
    }
    __syncthreads();
    const int cnt = s_cnt;
    const int cnt4 = (cnt + 3) & ~3;
    if (t >= cnt && t < cnt4) { s_C[t] = 0.f; s_nb[t] = 0; }  // pad slots

    // ---- phase 1b: gaussian smearing for active edges ----
    for (int idx = t; idx < cnt * GAUSS; idx += 256) {
        const int i = idx / GAUSS;
        const int g = idx - i * GAUSS;
        const float d = s_r[i] - (float)g * (5.0f / 24.0f);
        s_fij[i][g] = expf(-11.52f * d * d);   // -0.5/(5/24)^2 = -11.52
    }
    __syncthreads();

    // ---- phase 2: h1 = softplus(fij @ wf1 + bf1); pad rows -> 0 ----
    for (int idx = t; idx < cnt4 * FD; idx += 256) {
        const int i = idx >> 7;
        const int f = idx & (FD - 1);
        float acc = 0.f;
        if (i < cnt) {
            acc = bf1[f];
#pragma unroll
            for (int g = 0; g < GAUSS; ++g)
                acc += s_fij[i][g] * wf1[g * FD + f];
            acc = softplus_f(acc);
        }
        s_h1[i][f] = acc;
    }
    __syncthreads();

    // ---- phase 3: W = h1 @ wf2 + bf2, fused agg += W * C * y_j ----
    const int ty = t >> 4;          // 0..15  (k-tile slot)
    const int tx = t & 15;          // 0..15  (f-group)
    const int f0 = tx * 8;

    float out8[8];
#pragma unroll
    for (int j = 0; j < 8; ++j) out8[j] = 0.f;
    float b2[8];
#pragma unroll
    for (int j = 0; j < 8; ++j) b2[j] = bf2[f0 + j];

    const int ntiles = cnt4 >> 2;
    for (int tile = ty; tile < ntiles; tile += 16) {
        const int i0 = tile * 4;
        float acc[4][8];
#pragma unroll
        for (int kk = 0; kk < 4; ++kk)
#pragma unroll
            for (int j = 0; j < 8; ++j) acc[kk][j] = 0.f;

        for (int h = 0; h < FD; h += 4) {
            float4 a0 = *(const float4*)&s_h1[i0 + 0][h];
            float4 a1 = *(const float4*)&s_h1[i0 + 1][h];
            float4 a2 = *(const float4*)&s_h1[i0 + 2][h];
            float4 a3 = *(const float4*)&s_h1[i0 + 3][h];
            const float ar[4][4] = {
                {a0.x, a0.y, a0.z, a0.w},
                {a1.x, a1.y, a1.z, a1.w},
                {a2.x, a2.y, a2.z, a2.w},
                {a3.x, a3.y, a3.z, a3.w}};
#pragma unroll
            for (int hh = 0; hh < 4; ++hh) {
                const float4 w0 = *(const float4*)&wf2[(h + hh) * FD + f0];
                const float4 w1 = *(const float4*)&wf2[(h + hh) * FD + f0 + 4];
                const float wv[8] = {w0.x, w0.y, w0.z, w0.w,
                                     w1.x, w1.y, w1.z, w1.w};
#pragma unroll
                for (int kk = 0; kk < 4; ++kk) {
                    const float av = ar[kk][hh];
#pragma unroll
                    for (int j = 0; j < 8; ++j)
                        acc[kk][j] += av * wv[j];
                }
            }
        }
#pragma unroll
        for (int kk = 0; kk < 4; ++kk) {
            const int i = i0 + kk;
            const float c = s_C[i];
            const float* yj = y + (size_t)((b << 9) + s_nb[i]) * FD + f0;
            const float4 y0 = *(const float4*)yj;
            const float4 y1 = *(const float4*)(yj + 4);
            const float yv[8] = {y0.x, y0.y, y0.z, y0.w,
                                 y1.x, y1.y, y1.z, y1.w};
#pragma unroll
            for (int j = 0; j < 8; ++j)
                out8[j] += (acc[kk][j] + b2[j]) * c * yv[j];
        }
    }

#pragma unroll
    for (int j = 0; j < 8; ++j) s_red[ty][f0 + j] = out8[j];
    __syncthreads();
    if (t < FD) {
        float s = 0.f;
#pragma unroll
        for (int j = 0; j < 16; ++j) s += s_red[j][t];
        agg[atom * FD + t] = s;
    }
}

// K3: v = softplus(agg @ w_f2out + b_f2out) @ w_dense + b_dense
__global__ __launch_bounds__(128) void k3_post(
    const float* __restrict__ agg, const float* __restrict__ w_f2out,
    const float* __restrict__ b_f2out, const float* __restrict__ w_dense,
    const float* __restrict__ b_dense, float* __restrict__ v)
{
    const int atom = blockIdx.x;
    const int f = threadIdx.x;
    __shared__ float s_a[FD];
    __shared__ float s_t[FD];
    s_a[f] = agg[atom * FD + f];
    __syncthreads();
    float acc = b_f2out[f];
#pragma unroll 8
    for (int d = 0; d < FD; ++d) acc += s_a[d] * w_f2out[d * FD + f];
    s_t[f] = softplus_f(acc);
    __syncthreads();
    float acc2 = b_dense[f];
#pragma unroll 8
    for (int d = 0; d < FD; ++d) acc2 += s_t[d] * w_dense[d * FD + f];
    v[atom * FD + f] = acc2;
}

// K4: out[:, :, 128:] = v[b, label[b,n]]
__global__ __launch_bounds__(128) void k4_gather(
    const float* __restrict__ v, const int* __restrict__ label,
    float* __restrict__ out)
{
    const int atom = blockIdx.x;
    const int f = threadIdx.x;
    const int b = atom >> 9;
    const int l = label[atom];
    out[(size_t)atom * 256 + FD + f] = v[(size_t)((b << 9) + l) * FD + f];
}

extern "C" void kernel_launch(void* const* d_in, const int* in_sizes, int n_in,
                              void* d_out, int out_size, void* d_ws, size_t ws_size,
                              hipStream_t stream)
{
    const float* positions = (const float*)d_in[0];
    const float* cell      = (const float*)d_in[1];
    const float* coff      = (const float*)d_in[2];
    const float* nmask     = (const float*)d_in[3];
    const float* emb       = (const float*)d_in[4];
    const float* wf1       = (const float*)d_in[5];
    const float* bf1       = (const float*)d_in[6];
    const float* wf2       = (const float*)d_in[7];
    const float* bf2       = (const float*)d_in[8];
    const float* w_in2f    = (const float*)d_in[9];
    const float* w_f2out   = (const float*)d_in[10];
    const float* b_f2out   = (const float*)d_in[11];
    const float* w_dense   = (const float*)d_in[12];
    const float* b_dense   = (const float*)d_in[13];
    const int*   zn        = (const int*)d_in[14];
    const int*   nbr       = (const int*)d_in[15];
    const int*   label     = (const int*)d_in[16];

    float* out = (float*)d_out;
    float* ws  = (float*)d_ws;
    float* y   = ws;                 // [4096,128]
    float* agg = ws + BN * FD;       // [4096,128]
    float* v   = ws + 2 * BN * FD;   // [4096,128]

    hipLaunchKernelGGL(k1_embed_y, dim3(BN), dim3(FD), 0, stream,
                       emb, zn, w_in2f, y, out);
    hipLaunchKernelGGL(k2_conv, dim3(BN), dim3(256), 0, stream,
                       positions, cell, coff, nmask, wf1, bf1, wf2, bf2,
                       nbr, y, agg);
    hipLaunchKernelGGL(k3_post, dim3(BN), dim3(FD), 0, stream,
                       agg, w_f2out, b_f2out, w_dense, b_dense, v);
    hipLaunchKernelGGL(k4_gather, dim3(BN), dim3(FD), 0, stream,
                       v, label, out);
}

// Round 2
// 100.286 us; speedup vs baseline: 1.7212x; 1.7212x over previous
//
#include <hip/hip_runtime.h>
#include <cmath>

#define BN 4096      // B*N
#define NN 64
#define GAUSS 25
#define FD 128

typedef __attribute__((ext_vector_type(8))) short bf16x8;
typedef __attribute__((ext_vector_type(4))) float f32x4;

__device__ __forceinline__ float softplus_f(float x) {
    return fmaxf(x, 0.f) + log1pf(expf(-fabsf(x)));
}
__device__ __forceinline__ unsigned short f2b(float f) {
    unsigned int u = __float_as_uint(f);
    unsigned int r = (u + 0x7FFFu + ((u >> 16) & 1u)) >> 16;
    return (unsigned short)r;
}
__device__ __forceinline__ float b2f(unsigned short b) {
    return __uint_as_float(((unsigned int)b) << 16);
}
// swizzle byte address within a 256B row: flip bits 4-6 by row&7
__device__ __forceinline__ int SWZ(int row, int byte_off) {
    return byte_off ^ ((row & 7) << 4);
}

// K0: pack wf1 (pad K 25->32) and wf2 into bf16 MFMA B-fragment order.
// frag layout (16x16x32): lane l holds B[k = 8*(l>>4)+e][col = l&15], e=0..7
// wf1b[(ct*64 + l)*8 + e], ct = col-tile (8)
// wf2b[((s*8 + ct)*64 + l)*8 + e], s = K-step (4), ct = col-tile (8)
__global__ __launch_bounds__(256) void k0_prep(
    const float* __restrict__ wf1, const float* __restrict__ wf2,
    unsigned short* __restrict__ wf1b, unsigned short* __restrict__ wf2b)
{
    const int i = blockIdx.x * 256 + threadIdx.x;
    if (i < 4096) {
        const int e = i & 7, l = (i >> 3) & 63, ct = i >> 9;
        const int k = (l >> 4) * 8 + e, col = ct * 16 + (l & 15);
        wf1b[i] = (k < GAUSS) ? f2b(wf1[k * FD + col]) : 0;
    }
    if (i < 16384) {
        const int e = i & 7, l = (i >> 3) & 63, ct = (i >> 9) & 7, s = i >> 12;
        const int k = s * 32 + (l >> 4) * 8 + e, col = ct * 16 + (l & 15);
        wf2b[i] = f2b(wf2[k * FD + col]);
    }
}

// K1: x = emb[z]; write x to out[:, :128]; y = x @ w_in2f
__global__ __launch_bounds__(128) void k1_embed_y(
    const float* __restrict__ emb, const int* __restrict__ zn,
    const float* __restrict__ w_in2f, float* __restrict__ y,
    float* __restrict__ out)
{
    const int atom = blockIdx.x;
    const int f = threadIdx.x;
    __shared__ float s_x[FD];
    const int z = zn[atom];
    const float xv = emb[z * FD + f];
    s_x[f] = xv;
    out[(size_t)atom * 256 + f] = xv;
    __syncthreads();
    float acc = 0.f;
#pragma unroll 8
    for (int d = 0; d < FD; ++d)
        acc += s_x[d] * w_in2f[d * FD + f];
    y[atom * FD + f] = acc;
}

// K2: per-atom continuous-filter conv; filter net on bf16 MFMA
__global__ __launch_bounds__(256, 4) void k2_conv(
    const float* __restrict__ pos, const float* __restrict__ cell,
    const float* __restrict__ coff, const float* __restrict__ nmask,
    const unsigned short* __restrict__ wf1b, const float* __restrict__ bf1,
    const unsigned short* __restrict__ wf2b, const float* __restrict__ bf2,
    const int* __restrict__ nbr, const float* __restrict__ y,
    float* __restrict__ agg)
{
    const int atom = blockIdx.x;
    const int b = atom >> 9;
    const int t = threadIdx.x;

    __shared__ unsigned short s_fij[NN * 40];   // [64][32] pad-stride 40 (5KB)
    __shared__ unsigned short s_h1[NN * FD];    // swizzled [64][128] (16KB)
    __shared__ unsigned short s_yc[NN * FD];    // swizzled [64][128] (16KB)
    __shared__ float s_r[NN];
    __shared__ float s_C[NN];
    __shared__ int   s_nb[NN];
    __shared__ int   s_cnt;

    // ---- phase 1: distances + cutoff + wave-0 ballot compaction ----
    if (t < NN) {
        const int k = t;
        const int nb = nbr[atom * NN + k];
        const float m = nmask[atom * NN + k];
        const float* cb = cell + b * 9;
        const float* co = coff + (size_t)(atom * NN + k) * 3;
        const float ox = co[0]*cb[0] + co[1]*cb[3] + co[2]*cb[6];
        const float oy = co[0]*cb[1] + co[1]*cb[4] + co[2]*cb[7];
        const float oz = co[0]*cb[2] + co[1]*cb[5] + co[2]*cb[8];
        const float* pj = pos + (size_t)((b << 9) + nb) * 3;
        const float* pi = pos + (size_t)atom * 3;
        const float dx = pj[0] + ox - pi[0];
        const float dy = pj[1] + oy - pi[1];
        const float dz = pj[2] + oz - pi[2];
        const float d2 = dx*dx + dy*dy + dz*dz;
        const float r = sqrtf(m > 0.f ? d2 : 1.0f) * m;
        const float C = (r < 5.0f) ? m : 0.f;
        const bool active = (C != 0.f);
        const unsigned long long bal = __ballot(active);
        const int pre = __popcll(bal & ((1ull << k) - 1ull));
        const int mycnt = __popcll(bal);
        if (active) {
            s_r[pre]  = r;
            s_C[pre]  = C;
            s_nb[pre] = nb;
        }
        if (k >= mycnt) {          // pad slots (disjoint from compacted ones)
            s_r[k] = 0.f; s_C[k] = 0.f; s_nb[k] = 0;
        }
        if (k == 0) s_cnt = mycnt;
    }
    __syncthreads();
    const int cnt = s_cnt;
    if (cnt == 0) {
        if (t < FD) agg[(size_t)atom * FD + t] = 0.f;
        return;
    }
    const int Rt  = (cnt + 15) >> 4;   // row tiles of 16
    const int R16 = Rt * 16;

    // ---- phase 2a: gaussian features (bf16) into s_fij [R16][32] ----
    const float DW = 5.0f / 24.0f;
    const float CO = -0.5f / (DW * DW);
    for (int idx = t; idx < R16 * 32; idx += 256) {
        const int row = idx >> 5, k = idx & 31;
        float v = 0.f;
        if (row < cnt && k < GAUSS) {
            const float d = s_r[row] - (float)k * DW;
            v = expf(CO * d * d);
        }
        s_fij[row * 40 + k] = f2b(v);
    }
    // ---- phase 2b: yc[i][f] = C_i * y[nb_i][f] (bf16, swizzled) ----
    for (int idx = t; idx < R16 * 32; idx += 256) {
        const int row = idx >> 5, f0 = (idx & 31) * 4;
        const float c = s_C[row];
        const float4 yv = *(const float4*)&y[(size_t)((b << 9) + s_nb[row]) * FD + f0];
        unsigned short p[4] = { f2b(c*yv.x), f2b(c*yv.y), f2b(c*yv.z), f2b(c*yv.w) };
        *(uint2*)((char*)s_yc + SWZ(row, row * 256 + f0 * 2)) = *(uint2*)p;
    }
    __syncthreads();

    // ---- phase 3: h1 = softplus(fij @ wf1 + bf1) via MFMA -> s_h1 ----
    const int w    = t >> 6;
    const int lane = t & 63;
    const int lr   = lane & 15;   // row (A) / col (B,D) within tile
    const int lg   = lane >> 4;   // k-group / D row-group

    for (int rt = 0; rt < Rt; ++rt) {
        const bf16x8 a = *(const bf16x8*)&s_fij[(rt * 16 + lr) * 40 + lg * 8];
#pragma unroll
        for (int ci = 0; ci < 2; ++ci) {
            const int ct = w + 4 * ci;
            const bf16x8 bfrag = *(const bf16x8*)&wf1b[(ct * 64 + lane) * 8];
            f32x4 acc = {0.f, 0.f, 0.f, 0.f};
            acc = __builtin_amdgcn_mfma_f32_16x16x32_bf16(a, bfrag, acc, 0, 0, 0);
            const int col = ct * 16 + lr;
            const float bias = bf1[col];
#pragma unroll
            for (int r = 0; r < 4; ++r) {
                const int row = rt * 16 + lg * 4 + r;
                const float h = softplus_f(acc[r] + bias);
                const unsigned short hb = (row < cnt) ? f2b(h) : 0;
                *(unsigned short*)((char*)s_h1 + SWZ(row, row * 256 + col * 2)) = hb;
            }
        }
    }
    __syncthreads();

    // ---- phase 4: W = h1 @ wf2 + bf2; agg[f] = sum_i W[i,f]*yc[i,f] ----
#pragma unroll
    for (int ci = 0; ci < 2; ++ci) {
        const int ct2 = 2 * w + ci;
        const int col = ct2 * 16 + lr;
        const float bias = bf2[col];
        bf16x8 bs[4];
#pragma unroll
        for (int s = 0; s < 4; ++s)
            bs[s] = *(const bf16x8*)&wf2b[((s * 8 + ct2) * 64 + lane) * 8];
        float part = 0.f;
        for (int rt = 0; rt < Rt; ++rt) {
            f32x4 acc = {0.f, 0.f, 0.f, 0.f};
            const int arow = rt * 16 + lr;
#pragma unroll
            for (int s = 0; s < 4; ++s) {
                const bf16x8 a = *(const bf16x8*)((char*)s_h1 +
                    SWZ(arow, arow * 256 + (s * 32 + lg * 8) * 2));
                acc = __builtin_amdgcn_mfma_f32_16x16x32_bf16(a, bs[s], acc, 0, 0, 0);
            }
#pragma unroll
            for (int r = 0; r < 4; ++r) {
                const int row = rt * 16 + lg * 4 + r;
                const float yv = b2f(*(const unsigned short*)((char*)s_yc +
                    SWZ(row, row * 256 + col * 2)));
                part += (acc[r] + bias) * yv;   // yc=0 kills pad rows
            }
        }
        part += __shfl_xor(part, 16);
        part += __shfl_xor(part, 32);
        if (lg == 0) agg[(size_t)atom * FD + col] = part;
    }
}

// K3: v = softplus(agg @ w_f2out + b_f2out) @ w_dense + b_dense
__global__ __launch_bounds__(128) void k3_post(
    const float* __restrict__ agg, const float* __restrict__ w_f2out,
    const float* __restrict__ b_f2out, const float* __restrict__ w_dense,
    const float* __restrict__ b_dense, float* __restrict__ v)
{
    const int atom = blockIdx.x;
    const int f = threadIdx.x;
    __shared__ float s_a[FD];
    __shared__ float s_t[FD];
    s_a[f] = agg[atom * FD + f];
    __syncthreads();
    float acc = b_f2out[f];
#pragma unroll 8
    for (int d = 0; d < FD; ++d) acc += s_a[d] * w_f2out[d * FD + f];
    s_t[f] = softplus_f(acc);
    __syncthreads();
    float acc2 = b_dense[f];
#pragma unroll 8
    for (int d = 0; d < FD; ++d) acc2 += s_t[d] * w_dense[d * FD + f];
    v[atom * FD + f] = acc2;
}

// K4: out[:, :, 128:] = v[b, label[b,n]]
__global__ __launch_bounds__(128) void k4_gather(
    const float* __restrict__ v, const int* __restrict__ label,
    float* __restrict__ out)
{
    const int atom = blockIdx.x;
    const int f = threadIdx.x;
    const int b = atom >> 9;
    const int l = label[atom];
    out[(size_t)atom * 256 + FD + f] = v[(size_t)((b << 9) + l) * FD + f];
}

extern "C" void kernel_launch(void* const* d_in, const int* in_sizes, int n_in,
                              void* d_out, int out_size, void* d_ws, size_t ws_size,
                              hipStream_t stream)
{
    const float* positions = (const float*)d_in[0];
    const float* cell      = (const float*)d_in[1];
    const float* coff      = (const float*)d_in[2];
    const float* nmask     = (const float*)d_in[3];
    const float* emb       = (const float*)d_in[4];
    const float* wf1       = (const float*)d_in[5];
    const float* bf1       = (const float*)d_in[6];
    const float* wf2       = (const float*)d_in[7];
    const float* bf2       = (const float*)d_in[8];
    const float* w_in2f    = (const float*)d_in[9];
    const float* w_f2out   = (const float*)d_in[10];
    const float* b_f2out   = (const float*)d_in[11];
    const float* w_dense   = (const float*)d_in[12];
    const float* b_dense   = (const float*)d_in[13];
    const int*   zn        = (const int*)d_in[14];
    const int*   nbr       = (const int*)d_in[15];
    const int*   label     = (const int*)d_in[16];

    float* out = (float*)d_out;
    float* ws  = (float*)d_ws;
    float* y   = ws;                       // [4096,128] (reused as v)
    float* agg = ws + BN * FD;             // [4096,128]
    float* v   = y;                        // y dead after k2; alias
    unsigned short* wf1b = (unsigned short*)(ws + 2 * BN * FD);  // 4096
    unsigned short* wf2b = wf1b + 4096;                          // 16384

    hipLaunchKernelGGL(k0_prep, dim3(64), dim3(256), 0, stream,
                       wf1, wf2, wf1b, wf2b);
    hipLaunchKernelGGL(k1_embed_y, dim3(BN), dim3(FD), 0, stream,
                       emb, zn, w_in2f, y, out);
    hipLaunchKernelGGL(k2_conv, dim3(BN), dim3(256), 0, stream,
                       positions, cell, coff, nmask, wf1b, bf1, wf2b, bf2,
                       nbr, y, agg);
    hipLaunchKernelGGL(k3_post, dim3(BN), dim3(FD), 0, stream,
                       agg, w_f2out, b_f2out, w_dense, b_dense, v);
    hipLaunchKernelGGL(k4_gather, dim3(BN), dim3(FD), 0, stream,
                       v, label, out);
}

// Round 3
// 70.629 us; speedup vs baseline: 2.4440x; 1.4199x over previous
//
#include <hip/hip_runtime.h>
#include <cmath>

#define BN 4096      // B*N
#define NN 64
#define GAUSS 25
#define FD 128
#define APB 4        // atoms per block in k2

typedef __attribute__((ext_vector_type(8))) short bf16x8;
typedef __attribute__((ext_vector_type(4))) float f32x4;

__device__ __forceinline__ float softplus_f(float x) {
    // max(x,0) + log(1 + exp(-|x|)) with fast HW transcendentals
    const float t = __expf(-fabsf(x));
    return fmaxf(x, 0.f) + __logf(1.f + t);
}
__device__ __forceinline__ unsigned short f2b(float f) {
    unsigned int u = __float_as_uint(f);
    unsigned int r = (u + 0x7FFFu + ((u >> 16) & 1u)) >> 16;
    return (unsigned short)r;
}

// ---------------------------------------------------------------------------
// K0: pack wf1^T and wf2^T into bf16 MFMA A-fragment order (16x16x32).
// A-frag: lane l holds A[row = l&15][k = 8*(l>>4)+e], e=0..7.
// wf1tA[(ft*64+l)*8+e]          = wf1[g][f],  f=ft*16+(l&15), g=8*(l>>4)+e (g>=25 -> 0)
// wf2tA[((hs*8+ct)*64+l)*8+e]   = wf2[h][c],  c=ct*16+(l&15), h=hs*32+8*(l>>4)+e
// ---------------------------------------------------------------------------
__global__ __launch_bounds__(256) void k0_prep(
    const float* __restrict__ wf1, const float* __restrict__ wf2,
    unsigned short* __restrict__ wf1tA, unsigned short* __restrict__ wf2tA)
{
    const int i = blockIdx.x * 256 + threadIdx.x;
    if (i < 4096) {
        const int e = i & 7, l = (i >> 3) & 63, ft = i >> 9;
        const int f = ft * 16 + (l & 15);
        const int g = 8 * (l >> 4) + e;
        wf1tA[i] = (g < GAUSS) ? f2b(wf1[g * FD + f]) : (unsigned short)0;
    }
    if (i < 16384) {
        const int e = i & 7, l = (i >> 3) & 63, ct = (i >> 9) & 7, hs = i >> 12;
        const int c = ct * 16 + (l & 15);
        const int h = hs * 32 + 8 * (l >> 4) + e;
        wf2tA[i] = f2b(wf2[h * FD + c]);
    }
}

// ---------------------------------------------------------------------------
// K1: x = emb[z]; out[:, :128] = x (exact f32); y = x @ w_in2f (f32 VALU)
// 8 atoms / 256-thread block: weights read once per block (L1/L2 broadcast)
// ---------------------------------------------------------------------------
__global__ __launch_bounds__(256) void k1_embed_y(
    const float* __restrict__ emb, const int* __restrict__ zn,
    const float* __restrict__ w_in2f, float* __restrict__ y,
    float* __restrict__ out)
{
    const int al = threadIdx.x >> 5, l32 = threadIdx.x & 31;
    const int atom = blockIdx.x * 8 + al;
    const int c = l32 * 4;
    __shared__ float s_x[8][FD];
    const int z = zn[atom];
    const float4 xv = *(const float4*)&emb[z * FD + c];
    *(float4*)&s_x[al][c] = xv;
    *(float4*)&out[(size_t)atom * 256 + c] = xv;
    __syncthreads();
    float4 a0 = {0,0,0,0}, a1 = {0,0,0,0};
#pragma unroll 8
    for (int d = 0; d < FD; d += 2) {
        const float x0 = s_x[al][d], x1 = s_x[al][d + 1];
        const float4 w0 = *(const float4*)&w_in2f[d * FD + c];
        const float4 w1 = *(const float4*)&w_in2f[(d + 1) * FD + c];
        a0.x += x0 * w0.x; a0.y += x0 * w0.y; a0.z += x0 * w0.z; a0.w += x0 * w0.w;
        a1.x += x1 * w1.x; a1.y += x1 * w1.y; a1.z += x1 * w1.z; a1.w += x1 * w1.w;
    }
    const float4 yo = {a0.x + a1.x, a0.y + a1.y, a0.z + a1.z, a0.w + a1.w};
    *(float4*)&y[(size_t)atom * FD + c] = yo;
}

// ---------------------------------------------------------------------------
// K2: continuous-filter conv. 2 waves / block, 4 atoms sequentially.
// Both filter matmuls transposed so all LDS traffic is b64/b128 vectorized:
//   ph3: h1^T[f][edge] = wf1^T(A-regs) @ fij^T(B built in regs) -> LDS (swz b64)
//   ph4: W^T[c][edge]  = wf2^T(A-regs) @ h1^T(B from LDS b128); epilogue f32
// ---------------------------------------------------------------------------
__global__ __launch_bounds__(128, 2) void k2_conv(
    const float* __restrict__ pos, const float* __restrict__ cell,
    const float* __restrict__ coff, const float* __restrict__ nmask,
    const unsigned short* __restrict__ wf1tA, const float* __restrict__ bf1,
    const unsigned short* __restrict__ wf2tA, const float* __restrict__ bf2,
    const int* __restrict__ nbr, const float* __restrict__ y,
    float* __restrict__ agg)
{
    const int t = threadIdx.x;
    const int w = t >> 6, lane = t & 63, lr = lane & 15, lg = lane >> 4;

    __shared__ unsigned short s_h1[NN * FD];   // 16KB, swizzled [edge][f] bf16
    __shared__ float s_r[NN], s_C[NN];
    __shared__ int   s_nb[NN];
    __shared__ float s_bf1[FD], s_bf2[FD];
    __shared__ int   s_cnt;

    if (t < FD) { s_bf1[t] = bf1[t]; s_bf2[t] = bf2[t]; }

    // weight A-fragments in registers (loaded once per block)
    bf16x8 a1[4];      // wf1^T, f-tiles ft = 4w+i
#pragma unroll
    for (int i = 0; i < 4; ++i)
        a1[i] = *(const bf16x8*)&wf1tA[((4 * w + i) * 64 + lane) * 8];
    bf16x8 a2[4][4];   // wf2^T, [j: ct=4w+j][hs]
#pragma unroll
    for (int j = 0; j < 4; ++j)
#pragma unroll
        for (int hs = 0; hs < 4; ++hs)
            a2[j][hs] = *(const bf16x8*)&wf2tA[((hs * 8 + 4 * w + j) * 64 + lane) * 8];

    __syncthreads();

    const float DW = 5.0f / 24.0f;
    const float CO = -0.5f / (DW * DW);

    for (int a4 = 0; a4 < APB; ++a4) {
        const int atom = blockIdx.x * APB + a4;
        const int b = atom >> 9;

        // ---- phase 1: distances + cutoff + ballot compaction (wave 0) ----
        if (w == 0) {
            const int k = lane;
            const int nb = nbr[atom * NN + k];
            const float m = nmask[atom * NN + k];
            const float* cb = cell + b * 9;
            const float* co = coff + (size_t)(atom * NN + k) * 3;
            const float ox = co[0]*cb[0] + co[1]*cb[3] + co[2]*cb[6];
            const float oy = co[0]*cb[1] + co[1]*cb[4] + co[2]*cb[7];
            const float oz = co[0]*cb[2] + co[1]*cb[5] + co[2]*cb[8];
            const float* pj = pos + (size_t)((b << 9) + nb) * 3;
            const float* pi = pos + (size_t)atom * 3;
            const float dx = pj[0] + ox - pi[0];
            const float dy = pj[1] + oy - pi[1];
            const float dz = pj[2] + oz - pi[2];
            const float d2 = dx*dx + dy*dy + dz*dz;
            const float r = sqrtf(m > 0.f ? d2 : 1.0f) * m;
            const float C = (r < 5.0f) ? m : 0.f;
            const bool act = (C != 0.f);
            const unsigned long long bal = __ballot(act);
            const int pre = __popcll(bal & ((1ull << k) - 1ull));
            const int cnt0 = __popcll(bal);
            if (act) { s_r[pre] = r; s_C[pre] = C; s_nb[pre] = nb; }
            if (k >= cnt0) { s_r[k] = 1e20f; s_C[k] = 0.f; s_nb[k] = 0; }
            if (k == 0) s_cnt = cnt0;
        }
        __syncthreads();
        const int cnt = s_cnt;
        const int Rt = (cnt + 15) >> 4;   // 0..4 edge tiles of 16

        // ---- phase 3: h1^T tiles -> LDS ----
        for (int et = 0; et < Rt; ++et) {
            const float re = s_r[et * 16 + lr];
            bf16x8 bfij;
#pragma unroll
            for (int e = 0; e < 8; ++e) {
                const int g = 8 * lg + e;
                float v = 0.f;
                if (g < GAUSS) { const float d = re - (float)g * DW; v = __expf(CO * d * d); }
                bfij[e] = (short)f2b(v);
            }
            const int edge = et * 16 + lr;
            const int exor = (edge & 7) << 4;
#pragma unroll
            for (int i = 0; i < 4; ++i) {
                f32x4 acc = {0.f, 0.f, 0.f, 0.f};
                acc = __builtin_amdgcn_mfma_f32_16x16x32_bf16(a1[i], bfij, acc, 0, 0, 0);
                const int ft = 4 * w + i;
                const float4 b1 = *(const float4*)&s_bf1[ft * 16 + lg * 4];
                const unsigned int lo = (unsigned int)f2b(softplus_f(acc[0] + b1.x)) |
                                        ((unsigned int)f2b(softplus_f(acc[1] + b1.y)) << 16);
                const unsigned int hi = (unsigned int)f2b(softplus_f(acc[2] + b1.z)) |
                                        ((unsigned int)f2b(softplus_f(acc[3] + b1.w)) << 16);
                const int byte0 = edge * 256 + (ft * 16 + lg * 4) * 2;
                *(uint2*)((char*)s_h1 + (byte0 ^ exor)) = make_uint2(lo, hi);
            }
        }
        __syncthreads();

        // ---- phase 4: W^T tiles + fused C*y epilogue ----
        f32x4 part[4] = {{0,0,0,0},{0,0,0,0},{0,0,0,0},{0,0,0,0}};
        for (int et = 0; et < Rt; ++et) {
            const int edge = et * 16 + lr;
            const float Ce = s_C[edge];
            const float* yrow = y + (size_t)((b << 9) + s_nb[edge]) * FD;
            float4 yv[4];
#pragma unroll
            for (int j = 0; j < 4; ++j)
                yv[j] = *(const float4*)&yrow[(4 * w + j) * 16 + lg * 4];
            const int ebase = edge * 256;
            const int exor = (edge & 7) << 4;
            bf16x8 bh[4];
#pragma unroll
            for (int hs = 0; hs < 4; ++hs)
                bh[hs] = *(const bf16x8*)((char*)s_h1 + ((ebase + hs * 64 + lg * 16) ^ exor));
#pragma unroll
            for (int j = 0; j < 4; ++j) {
                f32x4 acc = {0.f, 0.f, 0.f, 0.f};
#pragma unroll
                for (int hs = 0; hs < 4; ++hs)
                    acc = __builtin_amdgcn_mfma_f32_16x16x32_bf16(a2[j][hs], bh[hs], acc, 0, 0, 0);
                const int c0 = (4 * w + j) * 16 + lg * 4;
                const float4 b2 = *(const float4*)&s_bf2[c0];
                part[j][0] += (acc[0] + b2.x) * Ce * yv[j].x;
                part[j][1] += (acc[1] + b2.y) * Ce * yv[j].y;
                part[j][2] += (acc[2] + b2.z) * Ce * yv[j].z;
                part[j][3] += (acc[3] + b2.w) * Ce * yv[j].w;
            }
        }
        // reduce over the 16 edge-lanes of each lane-group
#pragma unroll
        for (int j = 0; j < 4; ++j) {
#pragma unroll
            for (int m = 1; m <= 8; m <<= 1) {
                part[j][0] += __shfl_xor(part[j][0], m);
                part[j][1] += __shfl_xor(part[j][1], m);
                part[j][2] += __shfl_xor(part[j][2], m);
                part[j][3] += __shfl_xor(part[j][3], m);
            }
        }
        if (lr == 0) {
#pragma unroll
            for (int j = 0; j < 4; ++j) {
                const float4 o = {part[j][0], part[j][1], part[j][2], part[j][3]};
                *(float4*)&agg[(size_t)atom * FD + (4 * w + j) * 16 + lg * 4] = o;
            }
        }
        __syncthreads();   // protect s_* before next atom
    }
}

// ---------------------------------------------------------------------------
// K3: v = softplus(agg @ w_f2out + b_f2out) @ w_dense + b_dense (f32 VALU)
// 8 atoms / 256-thread block
// ---------------------------------------------------------------------------
__global__ __launch_bounds__(256) void k3_post(
    const float* __restrict__ agg, const float* __restrict__ w_f2out,
    const float* __restrict__ b_f2out, const float* __restrict__ w_dense,
    const float* __restrict__ b_dense, float* __restrict__ v)
{
    const int al = threadIdx.x >> 5, l32 = threadIdx.x & 31;
    const int atom = blockIdx.x * 8 + al;
    const int c = l32 * 4;
    __shared__ float s_a[8][FD];
    __shared__ float s_t[8][FD];
    *(float4*)&s_a[al][c] = *(const float4*)&agg[(size_t)atom * FD + c];
    __syncthreads();
    {
        float4 a0 = {0,0,0,0}, a1 = {0,0,0,0};
#pragma unroll 8
        for (int d = 0; d < FD; d += 2) {
            const float x0 = s_a[al][d], x1 = s_a[al][d + 1];
            const float4 w0 = *(const float4*)&w_f2out[d * FD + c];
            const float4 w1 = *(const float4*)&w_f2out[(d + 1) * FD + c];
            a0.x += x0 * w0.x; a0.y += x0 * w0.y; a0.z += x0 * w0.z; a0.w += x0 * w0.w;
            a1.x += x1 * w1.x; a1.y += x1 * w1.y; a1.z += x1 * w1.z; a1.w += x1 * w1.w;
        }
        const float4 b = *(const float4*)&b_f2out[c];
        s_t[al][c + 0] = softplus_f(a0.x + a1.x + b.x);
        s_t[al][c + 1] = softplus_f(a0.y + a1.y + b.y);
        s_t[al][c + 2] = softplus_f(a0.z + a1.z + b.z);
        s_t[al][c + 3] = softplus_f(a0.w + a1.w + b.w);
    }
    __syncthreads();
    {
        float4 a0 = {0,0,0,0}, a1 = {0,0,0,0};
#pragma unroll 8
        for (int d = 0; d < FD; d += 2) {
            const float x0 = s_t[al][d], x1 = s_t[al][d + 1];
            const float4 w0 = *(const float4*)&w_dense[d * FD + c];
            const float4 w1 = *(const float4*)&w_dense[(d + 1) * FD + c];
            a0.x += x0 * w0.x; a0.y += x0 * w0.y; a0.z += x0 * w0.z; a0.w += x0 * w0.w;
            a1.x += x1 * w1.x; a1.y += x1 * w1.y; a1.z += x1 * w1.z; a1.w += x1 * w1.w;
        }
        const float4 b = *(const float4*)&b_dense[c];
        const float4 o = {a0.x + a1.x + b.x, a0.y + a1.y + b.y,
                          a0.z + a1.z + b.z, a0.w + a1.w + b.w};
        *(float4*)&v[(size_t)atom * FD + c] = o;
    }
}

// K4: out[:, :, 128:] = v[b, label[b,n]]
__global__ __launch_bounds__(256) void k4_gather(
    const float* __restrict__ v, const int* __restrict__ label,
    float* __restrict__ out)
{
    const int al = threadIdx.x >> 5, l32 = threadIdx.x & 31;
    const int atom = blockIdx.x * 8 + al;
    const int b = atom >> 9;
    const int l = label[atom];
    const int c = l32 * 4;
    *(float4*)&out[(size_t)atom * 256 + FD + c] =
        *(const float4*)&v[(size_t)((b << 9) + l) * FD + c];
}

extern "C" void kernel_launch(void* const* d_in, const int* in_sizes, int n_in,
                              void* d_out, int out_size, void* d_ws, size_t ws_size,
                              hipStream_t stream)
{
    const float* positions = (const float*)d_in[0];
    const float* cell      = (const float*)d_in[1];
    const float* coff      = (const float*)d_in[2];
    const float* nmask     = (const float*)d_in[3];
    const float* emb       = (const float*)d_in[4];
    const float* wf1       = (const float*)d_in[5];
    const float* bf1       = (const float*)d_in[6];
    const float* wf2       = (const float*)d_in[7];
    const float* bf2       = (const float*)d_in[8];
    const float* w_in2f    = (const float*)d_in[9];
    const float* w_f2out   = (const float*)d_in[10];
    const float* b_f2out   = (const float*)d_in[11];
    const float* w_dense   = (const float*)d_in[12];
    const float* b_dense   = (const float*)d_in[13];
    const int*   zn        = (const int*)d_in[14];
    const int*   nbr       = (const int*)d_in[15];
    const int*   label     = (const int*)d_in[16];

    float* out = (float*)d_out;
    float* ws  = (float*)d_ws;
    float* y   = ws;                       // [4096,128]; dead after k2 -> alias v
    float* agg = ws + BN * FD;             // [4096,128]
    float* v   = y;
    unsigned short* wf1tA = (unsigned short*)(ws + 2 * BN * FD);  // 4096
    unsigned short* wf2tA = wf1tA + 4096;                         // 16384

    hipLaunchKernelGGL(k0_prep, dim3(64), dim3(256), 0, stream,
                       wf1, wf2, wf1tA, wf2tA);
    hipLaunchKernelGGL(k1_embed_y, dim3(BN / 8), dim3(256), 0, stream,
                       emb, zn, w_in2f, y, out);
    hipLaunchKernelGGL(k2_conv, dim3(BN / APB), dim3(128), 0, stream,
                       positions, cell, coff, nmask, wf1tA, bf1, wf2tA, bf2,
                       nbr, y, agg);
    hipLaunchKernelGGL(k3_post, dim3(BN / 8), dim3(256), 0, stream,
                       agg, w_f2out, b_f2out, w_dense, b_dense, v);
    hipLaunchKernelGGL(k4_gather, dim3(BN / 8), dim3(256), 0, stream,
                       v, label, out);
}

// Round 4
// 52.023 us; speedup vs baseline: 3.3180x; 1.3576x over previous
//
#include <hip/hip_runtime.h>
#include <cmath>

#define BN 4096      // B*N
#define NN 64
#define GAUSS 25
#define FD 128
#define APB 4        // atoms per block in k2

typedef __attribute__((ext_vector_type(8))) short bf16x8;
typedef __attribute__((ext_vector_type(4))) float f32x4;

__device__ __forceinline__ float softplus_f(float x) {
    const float t = __expf(-fabsf(x));
    return fmaxf(x, 0.f) + __logf(1.f + t);
}
__device__ __forceinline__ unsigned short f2b(float f) {
    unsigned int u = __float_as_uint(f);
    unsigned int r = (u + 0x7FFFu + ((u >> 16) & 1u)) >> 16;
    return (unsigned short)r;
}
__device__ __forceinline__ bf16x8 pack8(const float4 p0, const float4 p1) {
    bf16x8 r;
    r[0] = (short)f2b(p0.x); r[1] = (short)f2b(p0.y);
    r[2] = (short)f2b(p0.z); r[3] = (short)f2b(p0.w);
    r[4] = (short)f2b(p1.x); r[5] = (short)f2b(p1.y);
    r[6] = (short)f2b(p1.z); r[7] = (short)f2b(p1.w);
    return r;
}

// ---------------------------------------------------------------------------
// K0: pack weights into bf16 MFMA fragment order (16x16x32).
// B-frag layout: lane l holds B[k = ks*32 + 8*(l>>4)+e][col = ct*16 + (l&15)],
// stored at [((ks*8 + ct)*64 + l)*8 + e].  (A-frag of W^T == B-frag of W.)
// wf1tA: wf1 zero-padded K 25->32 (single ks).
// ---------------------------------------------------------------------------
__global__ __launch_bounds__(256) void k0_prep(
    const float* __restrict__ wf1, const float* __restrict__ wf2,
    const float* __restrict__ w_in2f, const float* __restrict__ w_f2out,
    const float* __restrict__ w_dense,
    unsigned short* __restrict__ wf1tA, unsigned short* __restrict__ wf2tA,
    unsigned short* __restrict__ win2fB, unsigned short* __restrict__ wf2outB,
    unsigned short* __restrict__ wdenseB)
{
    const int i = blockIdx.x * 256 + threadIdx.x;
    if (i < 4096) {
        const int e = i & 7, l = (i >> 3) & 63, ft = i >> 9;
        const int f = ft * 16 + (l & 15);
        const int g = 8 * (l >> 4) + e;
        wf1tA[i] = (g < GAUSS) ? f2b(wf1[g * FD + f]) : (unsigned short)0;
    }
    if (i < 16384) {
        const int e = i & 7, l = (i >> 3) & 63, ct = (i >> 9) & 7, ks = i >> 12;
        const int col = ct * 16 + (l & 15);
        const int k = ks * 32 + 8 * (l >> 4) + e;
        wf2tA[i]   = f2b(wf2[k * FD + col]);
        win2fB[i]  = f2b(w_in2f[k * FD + col]);
        wf2outB[i] = f2b(w_f2out[k * FD + col]);
        wdenseB[i] = f2b(w_dense[k * FD + col]);
    }
}

// ---------------------------------------------------------------------------
// K1: x = emb[z]; out[:, :128] = x (exact f32); y = bf16(x) @ win2fB via MFMA
// 1 wave / block, 16 atoms / block, 256 blocks.
// ---------------------------------------------------------------------------
__global__ __launch_bounds__(64) void k1_embed_y(
    const float* __restrict__ emb, const int* __restrict__ zn,
    const unsigned short* __restrict__ win2fB,
    float* __restrict__ y, float* __restrict__ out)
{
    const int lane = threadIdx.x, lr = lane & 15, lg = lane >> 4;
    const int atom0 = blockIdx.x * 16;
    const int atom = atom0 + lr;
    const int z = zn[atom];
    const float* xrow = emb + (size_t)z * FD;
    bf16x8 a[4];
#pragma unroll
    for (int ks = 0; ks < 4; ++ks) {
        const int c0 = ks * 32 + lg * 8;
        const float4 p0 = *(const float4*)&xrow[c0];
        const float4 p1 = *(const float4*)&xrow[c0 + 4];
        *(float4*)&out[(size_t)atom * 256 + c0] = p0;
        *(float4*)&out[(size_t)atom * 256 + c0 + 4] = p1;
        a[ks] = pack8(p0, p1);
    }
#pragma unroll
    for (int ct = 0; ct < 8; ++ct) {
        f32x4 acc = {0.f, 0.f, 0.f, 0.f};
#pragma unroll
        for (int ks = 0; ks < 4; ++ks)
            acc = __builtin_amdgcn_mfma_f32_16x16x32_bf16(
                a[ks], *(const bf16x8*)&win2fB[((ks * 8 + ct) * 64 + lane) * 8],
                acc, 0, 0, 0);
        const int col = ct * 16 + lr;
#pragma unroll
        for (int r = 0; r < 4; ++r)
            y[(size_t)(atom0 + lg * 4 + r) * FD + col] = acc[r];
    }
}

// ---------------------------------------------------------------------------
// K2: continuous-filter conv (unchanged from R3: transposed MFMA filter net)
// ---------------------------------------------------------------------------
__global__ __launch_bounds__(128, 2) void k2_conv(
    const float* __restrict__ pos, const float* __restrict__ cell,
    const float* __restrict__ coff, const float* __restrict__ nmask,
    const unsigned short* __restrict__ wf1tA, const float* __restrict__ bf1,
    const unsigned short* __restrict__ wf2tA, const float* __restrict__ bf2,
    const int* __restrict__ nbr, const float* __restrict__ y,
    float* __restrict__ agg)
{
    const int t = threadIdx.x;
    const int w = t >> 6, lane = t & 63, lr = lane & 15, lg = lane >> 4;

    __shared__ unsigned short s_h1[NN * FD];   // 16KB, swizzled [edge][f] bf16
    __shared__ float s_r[NN], s_C[NN];
    __shared__ int   s_nb[NN];
    __shared__ float s_bf1[FD], s_bf2[FD];
    __shared__ int   s_cnt;

    if (t < FD) { s_bf1[t] = bf1[t]; s_bf2[t] = bf2[t]; }

    bf16x8 a1[4];
#pragma unroll
    for (int i = 0; i < 4; ++i)
        a1[i] = *(const bf16x8*)&wf1tA[((4 * w + i) * 64 + lane) * 8];
    bf16x8 a2[4][4];
#pragma unroll
    for (int j = 0; j < 4; ++j)
#pragma unroll
        for (int hs = 0; hs < 4; ++hs)
            a2[j][hs] = *(const bf16x8*)&wf2tA[((hs * 8 + 4 * w + j) * 64 + lane) * 8];

    __syncthreads();

    const float DW = 5.0f / 24.0f;
    const float CO = -0.5f / (DW * DW);

    for (int a4 = 0; a4 < APB; ++a4) {
        const int atom = blockIdx.x * APB + a4;
        const int b = atom >> 9;

        if (w == 0) {
            const int k = lane;
            const int nb = nbr[atom * NN + k];
            const float m = nmask[atom * NN + k];
            const float* cb = cell + b * 9;
            const float* co = coff + (size_t)(atom * NN + k) * 3;
            const float ox = co[0]*cb[0] + co[1]*cb[3] + co[2]*cb[6];
            const float oy = co[0]*cb[1] + co[1]*cb[4] + co[2]*cb[7];
            const float oz = co[0]*cb[2] + co[1]*cb[5] + co[2]*cb[8];
            const float* pj = pos + (size_t)((b << 9) + nb) * 3;
            const float* pi = pos + (size_t)atom * 3;
            const float dx = pj[0] + ox - pi[0];
            const float dy = pj[1] + oy - pi[1];
            const float dz = pj[2] + oz - pi[2];
            const float d2 = dx*dx + dy*dy + dz*dz;
            const float r = sqrtf(m > 0.f ? d2 : 1.0f) * m;
            const float C = (r < 5.0f) ? m : 0.f;
            const bool act = (C != 0.f);
            const unsigned long long bal = __ballot(act);
            const int pre = __popcll(bal & ((1ull << k) - 1ull));
            const int cnt0 = __popcll(bal);
            if (act) { s_r[pre] = r; s_C[pre] = C; s_nb[pre] = nb; }
            if (k >= cnt0) { s_r[k] = 1e20f; s_C[k] = 0.f; s_nb[k] = 0; }
            if (k == 0) s_cnt = cnt0;
        }
        __syncthreads();
        const int cnt = s_cnt;
        const int Rt = (cnt + 15) >> 4;

        for (int et = 0; et < Rt; ++et) {
            const float re = s_r[et * 16 + lr];
            bf16x8 bfij;
#pragma unroll
            for (int e = 0; e < 8; ++e) {
                const int g = 8 * lg + e;
                float v = 0.f;
                if (g < GAUSS) { const float d = re - (float)g * DW; v = __expf(CO * d * d); }
                bfij[e] = (short)f2b(v);
            }
            const int edge = et * 16 + lr;
            const int exor = (edge & 7) << 4;
#pragma unroll
            for (int i = 0; i < 4; ++i) {
                f32x4 acc = {0.f, 0.f, 0.f, 0.f};
                acc = __builtin_amdgcn_mfma_f32_16x16x32_bf16(a1[i], bfij, acc, 0, 0, 0);
                const int ft = 4 * w + i;
                const float4 b1 = *(const float4*)&s_bf1[ft * 16 + lg * 4];
                const unsigned int lo = (unsigned int)f2b(softplus_f(acc[0] + b1.x)) |
                                        ((unsigned int)f2b(softplus_f(acc[1] + b1.y)) << 16);
                const unsigned int hi = (unsigned int)f2b(softplus_f(acc[2] + b1.z)) |
                                        ((unsigned int)f2b(softplus_f(acc[3] + b1.w)) << 16);
                const int byte0 = edge * 256 + (ft * 16 + lg * 4) * 2;
                *(uint2*)((char*)s_h1 + (byte0 ^ exor)) = make_uint2(lo, hi);
            }
        }
        __syncthreads();

        f32x4 part[4] = {{0,0,0,0},{0,0,0,0},{0,0,0,0},{0,0,0,0}};
        for (int et = 0; et < Rt; ++et) {
            const int edge = et * 16 + lr;
            const float Ce = s_C[edge];
            const float* yrow = y + (size_t)((b << 9) + s_nb[edge]) * FD;
            float4 yv[4];
#pragma unroll
            for (int j = 0; j < 4; ++j)
                yv[j] = *(const float4*)&yrow[(4 * w + j) * 16 + lg * 4];
            const int ebase = edge * 256;
            const int exor = (edge & 7) << 4;
            bf16x8 bh[4];
#pragma unroll
            for (int hs = 0; hs < 4; ++hs)
                bh[hs] = *(const bf16x8*)((char*)s_h1 + ((ebase + hs * 64 + lg * 16) ^ exor));
#pragma unroll
            for (int j = 0; j < 4; ++j) {
                f32x4 acc = {0.f, 0.f, 0.f, 0.f};
#pragma unroll
                for (int hs = 0; hs < 4; ++hs)
                    acc = __builtin_amdgcn_mfma_f32_16x16x32_bf16(a2[j][hs], bh[hs], acc, 0, 0, 0);
                const int c0 = (4 * w + j) * 16 + lg * 4;
                const float4 b2 = *(const float4*)&s_bf2[c0];
                part[j][0] += (acc[0] + b2.x) * Ce * yv[j].x;
                part[j][1] += (acc[1] + b2.y) * Ce * yv[j].y;
                part[j][2] += (acc[2] + b2.z) * Ce * yv[j].z;
                part[j][3] += (acc[3] + b2.w) * Ce * yv[j].w;
            }
        }
#pragma unroll
        for (int j = 0; j < 4; ++j) {
#pragma unroll
            for (int m = 1; m <= 8; m <<= 1) {
                part[j][0] += __shfl_xor(part[j][0], m);
                part[j][1] += __shfl_xor(part[j][1], m);
                part[j][2] += __shfl_xor(part[j][2], m);
                part[j][3] += __shfl_xor(part[j][3], m);
            }
        }
        if (lr == 0) {
#pragma unroll
            for (int j = 0; j < 4; ++j) {
                const float4 o = {part[j][0], part[j][1], part[j][2], part[j][3]};
                *(float4*)&agg[(size_t)atom * FD + (4 * w + j) * 16 + lg * 4] = o;
            }
        }
        __syncthreads();
    }
}

// ---------------------------------------------------------------------------
// K3: v = softplus(agg @ w_f2out + b) @ w_dense + b via MFMA.
// 1 wave / block, 16 atoms; t transposes through 4KB swizzled LDS.
// ---------------------------------------------------------------------------
__global__ __launch_bounds__(64) void k3_post(
    const float* __restrict__ agg, const unsigned short* __restrict__ wf2outB,
    const float* __restrict__ b_f2out, const unsigned short* __restrict__ wdenseB,
    const float* __restrict__ b_dense, float* __restrict__ v)
{
    const int lane = threadIdx.x, lr = lane & 15, lg = lane >> 4;
    const int atom0 = blockIdx.x * 16;
    __shared__ unsigned short s_t[16 * FD];   // 4KB

    bf16x8 a[4];
#pragma unroll
    for (int ks = 0; ks < 4; ++ks) {
        const float* p = &agg[(size_t)(atom0 + lr) * FD + ks * 32 + lg * 8];
        a[ks] = pack8(*(const float4*)p, *(const float4*)(p + 4));
    }
#pragma unroll
    for (int ct = 0; ct < 8; ++ct) {
        f32x4 acc = {0.f, 0.f, 0.f, 0.f};
#pragma unroll
        for (int ks = 0; ks < 4; ++ks)
            acc = __builtin_amdgcn_mfma_f32_16x16x32_bf16(
                a[ks], *(const bf16x8*)&wf2outB[((ks * 8 + ct) * 64 + lane) * 8],
                acc, 0, 0, 0);
        const int col = ct * 16 + lr;
        const float bias = b_f2out[col];
#pragma unroll
        for (int r = 0; r < 4; ++r) {
            const int row = lg * 4 + r;
            *(unsigned short*)((char*)s_t + ((row * 256 + col * 2) ^ ((row & 7) << 4)))
                = f2b(softplus_f(acc[r] + bias));
        }
    }
    __syncthreads();
    bf16x8 a2[4];
#pragma unroll
    for (int ks = 0; ks < 4; ++ks)
        a2[ks] = *(const bf16x8*)((char*)s_t +
                 ((lr * 256 + (ks * 32 + lg * 8) * 2) ^ ((lr & 7) << 4)));
#pragma unroll
    for (int ct = 0; ct < 8; ++ct) {
        f32x4 acc = {0.f, 0.f, 0.f, 0.f};
#pragma unroll
        for (int ks = 0; ks < 4; ++ks)
            acc = __builtin_amdgcn_mfma_f32_16x16x32_bf16(
                a2[ks], *(const bf16x8*)&wdenseB[((ks * 8 + ct) * 64 + lane) * 8],
                acc, 0, 0, 0);
        const int col = ct * 16 + lr;
        const float bias = b_dense[col];
#pragma unroll
        for (int r = 0; r < 4; ++r)
            v[(size_t)(atom0 + lg * 4 + r) * FD + col] = acc[r] + bias;
    }
}

// K4: out[:, :, 128:] = v[b, label[b,n]]
__global__ __launch_bounds__(256) void k4_gather(
    const float* __restrict__ v, const int* __restrict__ label,
    float* __restrict__ out)
{
    const int al = threadIdx.x >> 5, l32 = threadIdx.x & 31;
    const int atom = blockIdx.x * 8 + al;
    const int b = atom >> 9;
    const int l = label[atom];
    const int c = l32 * 4;
    *(float4*)&out[(size_t)atom * 256 + FD + c] =
        *(const float4*)&v[(size_t)((b << 9) + l) * FD + c];
}

extern "C" void kernel_launch(void* const* d_in, const int* in_sizes, int n_in,
                              void* d_out, int out_size, void* d_ws, size_t ws_size,
                              hipStream_t stream)
{
    const float* positions = (const float*)d_in[0];
    const float* cell      = (const float*)d_in[1];
    const float* coff      = (const float*)d_in[2];
    const float* nmask     = (const float*)d_in[3];
    const float* emb       = (const float*)d_in[4];
    const float* wf1       = (const float*)d_in[5];
    const float* bf1       = (const float*)d_in[6];
    const float* wf2       = (const float*)d_in[7];
    const float* bf2       = (const float*)d_in[8];
    const float* w_in2f    = (const float*)d_in[9];
    const float* w_f2out   = (const float*)d_in[10];
    const float* b_f2out   = (const float*)d_in[11];
    const float* w_dense   = (const float*)d_in[12];
    const float* b_dense   = (const float*)d_in[13];
    const int*   zn        = (const int*)d_in[14];
    const int*   nbr       = (const int*)d_in[15];
    const int*   label     = (const int*)d_in[16];

    float* out = (float*)d_out;
    float* ws  = (float*)d_ws;
    float* y   = ws;                       // [4096,128]; dead after k2 -> alias v
    float* agg = ws + BN * FD;             // [4096,128]
    float* v   = y;
    unsigned short* wf1tA   = (unsigned short*)(ws + 2 * BN * FD);  // 4096
    unsigned short* wf2tA   = wf1tA + 4096;                         // 16384
    unsigned short* win2fB  = wf2tA + 16384;                        // 16384
    unsigned short* wf2outB = win2fB + 16384;                       // 16384
    unsigned short* wdenseB = wf2outB + 16384;                      // 16384

    hipLaunchKernelGGL(k0_prep, dim3(64), dim3(256), 0, stream,
                       wf1, wf2, w_in2f, w_f2out, w_dense,
                       wf1tA, wf2tA, win2fB, wf2outB, wdenseB);
    hipLaunchKernelGGL(k1_embed_y, dim3(BN / 16), dim3(64), 0, stream,
                       emb, zn, win2fB, y, out);
    hipLaunchKernelGGL(k2_conv, dim3(BN / APB), dim3(128), 0, stream,
                       positions, cell, coff, nmask, wf1tA, bf1, wf2tA, bf2,
                       nbr, y, agg);
    hipLaunchKernelGGL(k3_post, dim3(BN / 16), dim3(64), 0, stream,
                       agg, wf2outB, b_f2out, wdenseB, b_dense, v);
    hipLaunchKernelGGL(k4_gather, dim3(BN / 8), dim3(256), 0, stream,
                       v, label, out);
}